// Round 3
// baseline (180.538 us; speedup 1.0000x reference)
//
#include <hip/hip_runtime.h>
#include <hip/hip_bf16.h>
#include <hip/hip_fp16.h>

// Problem constants
#define DM   256
#define NH   8
#define HC   32
#define SEQ  512
#define MTOT 1024

// ---------- workspace layout (byte offsets) ----------
#define B_X1   0            // fp32 x1 [1024][256]      1 MB
#define B_QH   (1u<<20)     // fp16 q  [16][512][32]    512 KB
#define B_KH   0x180000u    // fp16 k  [16][512][32]    512 KB
#define B_VT   0x200000u    // bf16 vT [16][32][512]    512 KB
#define B_WFCT 0x280000u    // bf16 WfcT  [1024][256]   512 KB
#define B_WPJT 0x300000u    // bf16 WprojT [256][1024]  512 KB
#define B_BAR  0x3C0000u    // global barrier counter (zeroed per launch)

typedef __attribute__((ext_vector_type(8))) __bf16 bf16x8;
typedef __attribute__((ext_vector_type(4))) __bf16 bf16x4;
typedef __attribute__((ext_vector_type(4))) float  f32x4;

__device__ __forceinline__ float qgelu(float x) {
    return x / (1.0f + __expf(-1.702f * x));
}

#define NBLK    256
#define BKP     264    // phase-1 B^T LDS row stride (k): 256 + 8 pad
#define QT      32     // phase-2 q rows per block
#define PSTRIDE 514
#define HSTR    264    // phase-3 h LDS row stride

// Grid-wide barrier: all NBLK blocks are co-resident (1 block/CU; LDS 37KB,
// launch_bounds(512) caps VGPR<=256 => the 8-wave block always fits one CU).
// Cumulative targets: counter never resets inside the kernel. threadfence =
// agent-scope release (wbl2) / acquire (inv) so normal stores cross XCD L2s.
__device__ __forceinline__ void gbar(unsigned* bar, unsigned target) {
    __syncthreads();
    if (threadIdx.x == 0) {
        __threadfence();   // release: flush this XCD's dirty lines
        __hip_atomic_fetch_add(bar, 1u, __ATOMIC_RELEASE, __HIP_MEMORY_SCOPE_AGENT);
        while (__hip_atomic_load(bar, __ATOMIC_ACQUIRE, __HIP_MEMORY_SCOPE_AGENT) < target)
            __builtin_amdgcn_s_sleep(2);
        __threadfence();   // acquire: invalidate stale L1/L2 lines
    }
    __syncthreads();
}

// ---------------------------------------------------------------------------
// Fused kernel: phase1 QKV GEMM + weight transposes -> gbar -> phase2
// L1-distance attention (+residual, out preinit) -> gbar -> phase3 MLP.
// 256 blocks x 512 threads, one block per CU, resident for the whole op.
// Removes two kernel-boundary drains + dispatch ramps of the 3-kernel chain.
// ---------------------------------------------------------------------------
__global__ __launch_bounds__(512)
void fused_k(const float* __restrict__ x, const float* __restrict__ W,
             const float* __restrict__ bias,
             const float* __restrict__ Wfc, const float* __restrict__ Wproj,
             const float* __restrict__ bfc, const float* __restrict__ bproj,
             char* __restrict__ wsb, float* __restrict__ out)
{
    __shared__ __align__(16) unsigned char SM[37 * 1024];
    const int tid = threadIdx.x;
    const int bid = blockIdx.x;
    unsigned* bar = (unsigned*)(wsb + B_BAR);

    float* x1 = (float*)(wsb + B_X1);
    __half*  qhg = (__half*)(wsb + B_QH);
    __half*  khg = (__half*)(wsb + B_KH);
    __bf16*  vtb = (__bf16*)(wsb + B_VT);

    // ================= Phase 1: QKV GEMM + Wfc/Wproj transposes ===========
    // 896 virtual 256-thread blocks: vb 0..767 GEMM tiles, 768..895
    // transposes. Folded as 2 sub-blocks per real block x 2 passes; the
    // produce->consume barrier is hoisted to a common __syncthreads.
    for (int pass = 0; pass < 2; ++pass) {
        const int sub = tid >> 8;              // 0/1
        const int vt  = tid & 255;
        const int vb  = pass * 512 + bid * 2 + sub;
        unsigned char* SB = SM + sub * 16640;  // per-sub 16.6KB blob
        float*  lt  = (float*)SB;              // transpose path: [64][65] f32
        __bf16* lbt = (__bf16*)SB;             // GEMM path: [16][BKP] bf16

        const bool gemm = (vb < 768);
        const bool tp   = (vb >= 768) && (vb < 896);

        // ---- produce into LDS ----
        if (gemm) {
            const int n0 = (vb >> 4) * 16;
            const int kk = vt >> 2, c4 = (vt & 3) * 4;
            #pragma unroll
            for (int p = 0; p < 4; ++p) {
                const int k = p * 64 + kk;
                float4 w = *(const float4*)&W[(size_t)k * 768 + n0 + c4];
                lbt[(c4 + 0) * BKP + k] = (__bf16)w.x;
                lbt[(c4 + 1) * BKP + k] = (__bf16)w.y;
                lbt[(c4 + 2) * BKP + k] = (__bf16)w.z;
                lbt[(c4 + 3) * BKP + k] = (__bf16)w.w;
            }
        } else if (tp) {
            const int tt = vb - 768;
            const float* src; int K, N, tile;
            if (tt < 64) { src = Wfc;   K = 256;  N = 1024; tile = tt; }
            else         { src = Wproj; K = 1024; N = 256;  tile = tt - 64; }
            const int nn = N >> 6;
            const int k0 = (tile / nn) * 64, n0t = (tile % nn) * 64;
            const int rr0 = vt >> 4, c4 = vt & 15;
            #pragma unroll
            for (int i = 0; i < 4; ++i) {
                const int rr = rr0 + i * 16;
                float4 v = *(const float4*)&src[(size_t)(k0 + rr) * N + n0t + c4 * 4];
                lt[rr * 65 + c4 * 4 + 0] = v.x; lt[rr * 65 + c4 * 4 + 1] = v.y;
                lt[rr * 65 + c4 * 4 + 2] = v.z; lt[rr * 65 + c4 * 4 + 3] = v.w;
            }
        }
        __syncthreads();

        // ---- consume ----
        if (gemm) {
            const int lane = vt & 63, wv = vt >> 6;
            const int n0 = (vb >> 4) * 16;
            const int m0 = ((vb * 4 + wv) & 63) * 16;
            const int r = lane & 15, q = lane >> 4;
            const float*  ap = x + (size_t)(m0 + r) * DM + q * 8;
            const __bf16* bl = &lbt[r * BKP + q * 8];
            f32x4 acc = {0.f, 0.f, 0.f, 0.f};
            #pragma unroll
            for (int kt = 0; kt < DM; kt += 32) {
                float4 a0 = *(const float4*)(ap + kt);
                float4 a1 = *(const float4*)(ap + kt + 4);
                bf16x8 af;
                af[0] = (__bf16)a0.x; af[1] = (__bf16)a0.y; af[2] = (__bf16)a0.z; af[3] = (__bf16)a0.w;
                af[4] = (__bf16)a1.x; af[5] = (__bf16)a1.y; af[6] = (__bf16)a1.z; af[7] = (__bf16)a1.w;
                bf16x8 bf = *(const bf16x8*)(bl + kt);
                acc = __builtin_amdgcn_mfma_f32_16x16x32_bf16(af, bf, acc, 0, 0, 0);
            }
            const int n = n0 + r;
            const float bn = bias[n];
            const int h = n / 96, jj = n % 96;
            #pragma unroll
            for (int i = 0; i < 4; ++i) {
                const int m = m0 + q * 4 + i;
                const float v = acc[i] + bn;
                const int b = m >> 9, t = m & 511;
                const int bh = b * NH + h;
                if (jj < 32)      qhg[((size_t)(bh * SEQ + t)) * HC + jj]        = (__half)v;
                else if (jj < 64) khg[((size_t)(bh * SEQ + t)) * HC + (jj - 32)] = (__half)v;
                else              vtb[((size_t)(bh * HC + (jj - 64))) * SEQ + t] = (__bf16)v;
            }
        } else if (tp) {
            const int tt = vb - 768;
            __bf16* dst; int K, N, tile;
            if (tt < 64) { dst = (__bf16*)(wsb + B_WFCT); K = 256;  N = 1024; tile = tt; }
            else         { dst = (__bf16*)(wsb + B_WPJT); K = 1024; N = 256;  tile = tt - 64; }
            const int nn = N >> 6;
            const int k0 = (tile / nn) * 64, n0t = (tile % nn) * 64;
            const int rr0 = vt >> 4, c4 = vt & 15;
            #pragma unroll
            for (int i = 0; i < 4; ++i) {
                const int rr = rr0 + i * 16;
                bf16x4 bv;
                bv.x = (__bf16)lt[(c4 * 4 + 0) * 65 + rr];
                bv.y = (__bf16)lt[(c4 * 4 + 1) * 65 + rr];
                bv.z = (__bf16)lt[(c4 * 4 + 2) * 65 + rr];
                bv.w = (__bf16)lt[(c4 * 4 + 3) * 65 + rr];
                *(bf16x4*)&dst[(size_t)(n0t + rr) * K + k0 + c4 * 4] = bv;
            }
        }
        __syncthreads();
    }

    gbar(bar, NBLK);

    // ================= Phase 2: attention (QT=32 rows per block) ===========
    {
        __bf16*  pmat  = (__bf16*)SM;                 // 32*514*2 = 32896 B
        __half2* qtile = (__half2*)(SM + 32896);      // 32*16*4  =  2048 B
        float*   psum  = (float*)(SM + 34944);        // 32*8*4   =  1024 B
        float*   pinv  = (float*)(SM + 35968);        // 32*4     =   128 B

        const int lane = tid & 63;
        const int wv   = tid >> 6;
        const int sg   = tid;                          // s index 0..511
        const int bh   = bid >> 4;
        const int qbase = (bid & 15) * QT;
        const float scale = 0.17677669529663687f;      // 1/sqrt(32)

        const __half2* kp = (const __half2*)(khg + ((size_t)(bh * SEQ + sg)) * HC);
        __half2 kr[16];
        #pragma unroll
        for (int j = 0; j < 16; ++j) kr[j] = kp[j];

        {   // 512 threads load the 32x16 half2 q tile
            const int t = tid >> 4, j = tid & 15;
            qtile[t * 16 + j] =
                *(const __half2*)(qhg + ((size_t)(bh * SEQ + qbase + t)) * HC + j * 2);
        }
        __syncthreads();

        #pragma unroll 4
        for (int t = 0; t < QT; ++t) {
            __half2 acc2 = __floats2half2_rn(0.f, 0.f);
            #pragma unroll
            for (int j = 0; j < 16; ++j) {
                __half2 dif = __hsub2(kr[j], qtile[t * 16 + j]);
                unsigned u = (*(unsigned*)&dif) & 0x7FFF7FFFu;
                acc2 = __hadd2(acc2, *(__half2*)&u);
            }
            const float d = __low2float(acc2) + __high2float(acc2);
            float w = 1.0f / (0.001f + d * scale);
            if (sg == qbase + t) w = 0.0f;
            float p = __expf(w);
            float se = p;
            #pragma unroll
            for (int off = 32; off >= 1; off >>= 1) se += __shfl_xor(se, off, 64);
            pmat[t * PSTRIDE + sg] = (__bf16)p;
            if (lane == 0) psum[t * 8 + wv] = se;
        }
        __syncthreads();

        if (tid < QT) {
            float s = 0.f;
            #pragma unroll
            for (int j = 0; j < 8; ++j) s += psum[tid * 8 + j];
            pinv[tid] = 1.0f / s;
        }
        __syncthreads();

        if (wv < 4) {
            const int mq = wv >> 1, nc = wv & 1;       // t-tile, c-tile
            const int r = lane & 15, q = lane >> 4;
            const __bf16* bp  = vtb + ((size_t)(bh * HC + nc * 16 + r)) * SEQ + q * 8;
            const __bf16* apm = &pmat[(mq * 16 + r) * PSTRIDE + q * 8];
            f32x4 acc = {0.f, 0.f, 0.f, 0.f};
            #pragma unroll
            for (int kt = 0; kt < SEQ; kt += 32) {
                bf16x8 af = *(const bf16x8*)(apm + kt);
                bf16x8 bf = *(const bf16x8*)(bp + kt);
                acc = __builtin_amdgcn_mfma_f32_16x16x32_bf16(af, bf, acc, 0, 0, 0);
            }
            const int b = bh >> 3, hh = bh & 7;
            const int col = hh * HC + nc * 16 + r;
            const float bpn = bproj[col];
            #pragma unroll
            for (int i = 0; i < 4; ++i) {
                const int tl = mq * 16 + q * 4 + i;
                const int t  = qbase + tl;
                const float v = acc[i] * pinv[tl];
                const int idx = ((b * SEQ + t) * DM) + col;
                const float res = x[idx] + v;
                x1[idx]  = res;
                out[idx] = res + bpn;   // base; phase 3 atomically adds h@Wproj
            }
        }
    }

    gbar(bar, 2 * NBLK);

    // ================= Phase 3: MLP, split-K x4, atomic accumulate =========
    {
        __bf16* hs = (__bf16*)SM;                      // [16][HSTR] = 8448 B
        const __bf16* Wf = (const __bf16*)(wsb + B_WFCT);
        const __bf16* Wp = (const __bf16*)(wsb + B_WPJT);

        const int lane = tid & 63;
        const int wv   = tid >> 6;                     // 0..7
        const int mt   = bid & 63;
        const int ns   = bid >> 6;                     // k/n slab 0..3
        const int m0   = mt * 16;
        const int r    = lane & 15, q = lane >> 4;

        // ---- FC phase: h[16][ns*256 .. +256) ----
        {
            const float* ap = x1 + (size_t)(m0 + r) * DM + q * 8;
            f32x4 acc[2] = {};
            #pragma unroll
            for (int kt = 0; kt < DM; kt += 32) {
                float4 a0 = *(const float4*)(ap + kt);
                float4 a1 = *(const float4*)(ap + kt + 4);
                bf16x8 af;
                af[0] = (__bf16)a0.x; af[1] = (__bf16)a0.y; af[2] = (__bf16)a0.z; af[3] = (__bf16)a0.w;
                af[4] = (__bf16)a1.x; af[5] = (__bf16)a1.y; af[6] = (__bf16)a1.z; af[7] = (__bf16)a1.w;
                #pragma unroll
                for (int nt = 0; nt < 2; ++nt) {
                    const int n0 = ns * 256 + (wv * 2 + nt) * 16;
                    bf16x8 bf = *(const bf16x8*)(Wf + (size_t)(n0 + r) * DM + q * 8 + kt);
                    acc[nt] = __builtin_amdgcn_mfma_f32_16x16x32_bf16(af, bf, acc[nt], 0, 0, 0);
                }
            }
            #pragma unroll
            for (int nt = 0; nt < 2; ++nt) {
                const int nl = (wv * 2 + nt) * 16 + r;
                const float bn = bfc[ns * 256 + nl];
                #pragma unroll
                for (int i = 0; i < 4; ++i)
                    hs[(q * 4 + i) * HSTR + nl] = (__bf16)qgelu(acc[nt][i] + bn);
            }
        }
        __syncthreads();

        // ---- PROJ phase: out[m0..+16][wv*32..+32) += h_slab @ Wp k-slice ----
        {
            f32x4 acc[2] = {};
            const __bf16* al = &hs[r * HSTR + q * 8];
            #pragma unroll
            for (int kt = 0; kt < 256; kt += 32) {
                bf16x8 af = *(const bf16x8*)(al + kt);
                #pragma unroll
                for (int nt = 0; nt < 2; ++nt) {
                    const int n0 = wv * 32 + nt * 16;
                    bf16x8 bf = *(const bf16x8*)(Wp + (size_t)(n0 + r) * 1024 +
                                                 ns * 256 + q * 8 + kt);
                    acc[nt] = __builtin_amdgcn_mfma_f32_16x16x32_bf16(af, bf, acc[nt], 0, 0, 0);
                }
            }
            #pragma unroll
            for (int nt = 0; nt < 2; ++nt) {
                const int n = wv * 32 + nt * 16 + r;
                #pragma unroll
                for (int i = 0; i < 4; ++i) {
                    const int m = m0 + q * 4 + i;
                    atomicAdd(&out[(size_t)m * DM + n], acc[nt][i]);
                }
            }
        }
    }
}

// ---------------------------------------------------------------------------
extern "C" void kernel_launch(void* const* d_in, const int* in_sizes, int n_in,
                              void* d_out, int out_size, void* d_ws, size_t ws_size,
                              hipStream_t stream)
{
    (void)in_sizes; (void)n_in; (void)out_size; (void)ws_size;
    const float* x     = (const float*)d_in[0];
    const float* Wqkv  = (const float*)d_in[1];
    const float* bqkv  = (const float*)d_in[2];
    const float* Wfc   = (const float*)d_in[3];
    const float* bfc   = (const float*)d_in[4];
    const float* Wproj = (const float*)d_in[5];
    const float* bproj = (const float*)d_in[6];
    float* out = (float*)d_out;
    char*  wsb = (char*)d_ws;

    hipMemsetAsync(wsb + B_BAR, 0, 64, stream);   // zero barrier counter
    fused_k<<<NBLK, 512, 0, stream>>>(x, Wqkv, bqkv, Wfc, Wproj,
                                      bfc, bproj, wsb, out);
}

// Round 4
// 106.251 us; speedup vs baseline: 1.6992x; 1.6992x over previous
//
#include <hip/hip_runtime.h>
#include <hip/hip_bf16.h>
#include <hip/hip_fp16.h>

// Problem constants
#define DM   256
#define NH   8
#define HC   32
#define SEQ  512
#define MTOT 1024

// ---------- workspace layout (byte offsets) ----------
#define B_X1   0            // fp32 x1 [1024][256]      1 MB
#define B_QH   (1u<<20)     // fp16 q  [16][512][32]    512 KB
#define B_KH   0x180000u    // fp16 k  [16][512][32]    512 KB
#define B_VT   0x200000u    // bf16 vT [16][32][512]    512 KB
#define B_WFCT 0x280000u    // bf16 WfcT  [1024][256]   512 KB
#define B_WPJT 0x300000u    // bf16 WprojT [256][1024]  512 KB

typedef __attribute__((ext_vector_type(8))) __bf16 bf16x8;
typedef __attribute__((ext_vector_type(4))) __bf16 bf16x4;
typedef __attribute__((ext_vector_type(4))) float  f32x4;

__device__ __forceinline__ float qgelu(float x) {
    return x / (1.0f + __expf(-1.702f * x));
}

// ---------------------------------------------------------------------------
// K1: QKV GEMM (1024x768, K=256) + side-car weight transposes (round-2
// proven, unchanged). B-panel staged once through LDS; MFMA loop reads one
// ds_read_b128 per K-step. Blocks 768..895: 64x64 transposes of Wfc/Wproj.
// ---------------------------------------------------------------------------
#define BKP 264   // lbt row stride (k) in elements: 256 + 8 pad

__global__ __launch_bounds__(256)
void qkv_k(const float* __restrict__ x, const float* __restrict__ W,
           const float* __restrict__ bias,
           const float* __restrict__ Wfc, const float* __restrict__ Wproj,
           char* __restrict__ wsb)
{
    __shared__ float lt[64 * 65];
    __shared__ __align__(16) __bf16 lbt[16 * BKP];   // B^T panel, 8.25 KB
    const int bid = blockIdx.x, tid = threadIdx.x;

    if (bid >= 768) {
        const int tt = bid - 768;
        const float* src; __bf16* dst; int K, N, tile;
        if (tt < 64) { src = Wfc;   dst = (__bf16*)(wsb + B_WFCT); K = 256;  N = 1024; tile = tt; }
        else         { src = Wproj; dst = (__bf16*)(wsb + B_WPJT); K = 1024; N = 256;  tile = tt - 64; }
        const int nn = N >> 6;
        const int k0 = (tile / nn) * 64, n0 = (tile % nn) * 64;
        const int rr0 = tid >> 4, c4 = tid & 15;
        #pragma unroll
        for (int i = 0; i < 4; ++i) {
            const int rr = rr0 + i * 16;
            float4 v = *(const float4*)&src[(size_t)(k0 + rr) * N + n0 + c4 * 4];
            lt[rr * 65 + c4 * 4 + 0] = v.x; lt[rr * 65 + c4 * 4 + 1] = v.y;
            lt[rr * 65 + c4 * 4 + 2] = v.z; lt[rr * 65 + c4 * 4 + 3] = v.w;
        }
        __syncthreads();
        #pragma unroll
        for (int i = 0; i < 4; ++i) {
            const int rr = rr0 + i * 16;
            bf16x4 b;
            b.x = (__bf16)lt[(c4 * 4 + 0) * 65 + rr];
            b.y = (__bf16)lt[(c4 * 4 + 1) * 65 + rr];
            b.z = (__bf16)lt[(c4 * 4 + 2) * 65 + rr];
            b.w = (__bf16)lt[(c4 * 4 + 3) * 65 + rr];
            *(bf16x4*)&dst[(size_t)(n0 + rr) * K + k0 + c4 * 4] = b;
        }
        return;
    }

    const int lane = tid & 63, wv = tid >> 6;
    const int n0 = (bid >> 4) * 16;                   // shared by all 4 waves
    const int m0 = ((bid * 4 + wv) & 63) * 16;
    const int r = lane & 15, q = lane >> 4;

    // ---- cooperative stage: W[0:256][n0:n0+16] -> lbt[n][k] bf16 ----
    {
        const int kk = tid >> 2;            // 0..63
        const int c4 = (tid & 3) * 4;       // 0,4,8,12
        #pragma unroll
        for (int p = 0; p < 4; ++p) {
            const int k = p * 64 + kk;
            float4 w = *(const float4*)&W[(size_t)k * 768 + n0 + c4];
            lbt[(c4 + 0) * BKP + k] = (__bf16)w.x;
            lbt[(c4 + 1) * BKP + k] = (__bf16)w.y;
            lbt[(c4 + 2) * BKP + k] = (__bf16)w.z;
            lbt[(c4 + 3) * BKP + k] = (__bf16)w.w;
        }
    }
    __syncthreads();

    const float*  ap = x + (size_t)(m0 + r) * DM + q * 8;
    const __bf16* bl = &lbt[r * BKP + q * 8];

    f32x4 acc = {0.f, 0.f, 0.f, 0.f};
    #pragma unroll
    for (int kt = 0; kt < DM; kt += 32) {
        float4 a0 = *(const float4*)(ap + kt);
        float4 a1 = *(const float4*)(ap + kt + 4);
        bf16x8 af;
        af[0] = (__bf16)a0.x; af[1] = (__bf16)a0.y; af[2] = (__bf16)a0.z; af[3] = (__bf16)a0.w;
        af[4] = (__bf16)a1.x; af[5] = (__bf16)a1.y; af[6] = (__bf16)a1.z; af[7] = (__bf16)a1.w;
        bf16x8 bf = *(const bf16x8*)(bl + kt);
        acc = __builtin_amdgcn_mfma_f32_16x16x32_bf16(af, bf, acc, 0, 0, 0);
    }

    __half*  qh  = (__half*)(wsb + B_QH);
    __half*  kh  = (__half*)(wsb + B_KH);
    __bf16*  vtb = (__bf16*)(wsb + B_VT);
    const int n = n0 + r;                 // C col = lane&15
    const float bn = bias[n];
    const int h = n / 96, jj = n % 96;
    #pragma unroll
    for (int i = 0; i < 4; ++i) {
        const int m = m0 + q * 4 + i;     // C row = q*4 + i
        const float v = acc[i] + bn;
        const int b = m >> 9, t = m & 511;
        const int bh = b * NH + h;
        if (jj < 32)      qh[((size_t)(bh * SEQ + t)) * HC + jj]        = (__half)v;
        else if (jj < 64) kh[((size_t)(bh * SEQ + t)) * HC + (jj - 32)] = (__half)v;
        else              vtb[((size_t)(bh * HC + (jj - 64))) * SEQ + t] = (__bf16)v;
    }
}

// ---------------------------------------------------------------------------
// K2: L1-distance attention + residual (unchanged, harness-verified).
// ---------------------------------------------------------------------------
#define QT 16
#define PSTRIDE 514

__global__ __launch_bounds__(512, 4)
void attn_k(const char* __restrict__ wsb, const float* __restrict__ xin,
            float* __restrict__ x1, const float* __restrict__ bproj,
            float* __restrict__ out)
{
    __shared__ __half2 qtile[QT * 16];
    __shared__ __bf16  pmat[QT * PSTRIDE];
    __shared__ float   psum[QT * 8];
    __shared__ float   pinv[QT];

    const __half*  qhg = (const __half*)(wsb + B_QH);
    const __half*  khg = (const __half*)(wsb + B_KH);
    const __bf16*  vtb = (const __bf16*)(wsb + B_VT);

    const int tid  = threadIdx.x;
    const int lane = tid & 63;
    const int wv   = tid >> 6;
    const int sg   = tid;                       // s index
    const int bh   = blockIdx.x >> 5;
    const int qbase = (blockIdx.x & 31) * QT;
    const float scale = 0.17677669529663687f;   // 1/sqrt(32)

    const __half2* kp = (const __half2*)(khg + ((size_t)(bh * SEQ + sg)) * HC);
    __half2 kr[16];
    #pragma unroll
    for (int j = 0; j < 16; ++j) kr[j] = kp[j];

    if (tid < 256) {
        const int t = tid >> 4, j = tid & 15;
        qtile[t * 16 + j] =
            *(const __half2*)(qhg + ((size_t)(bh * SEQ + qbase + t)) * HC + j * 2);
    }
    __syncthreads();

    #pragma unroll 4
    for (int t = 0; t < QT; ++t) {
        __half2 acc2 = __floats2half2_rn(0.f, 0.f);
        #pragma unroll
        for (int j = 0; j < 16; ++j) {
            __half2 dif = __hsub2(kr[j], qtile[t * 16 + j]);   // LDS broadcast
            unsigned u = (*(unsigned*)&dif) & 0x7FFF7FFFu;     // packed |.|
            acc2 = __hadd2(acc2, *(__half2*)&u);
        }
        const float d = __low2float(acc2) + __high2float(acc2);
        float w = 1.0f / (0.001f + d * scale);
        if (sg == qbase + t) w = 0.0f;          // diagonal
        float p = __expf(w);                    // w bounded: no max pass
        float se = p;
        #pragma unroll
        for (int off = 32; off >= 1; off >>= 1) se += __shfl_xor(se, off, 64);
        pmat[t * PSTRIDE + sg] = (__bf16)p;
        if (lane == 0) psum[t * 8 + wv] = se;
    }
    __syncthreads();

    if (tid < QT) {
        float s = 0.f;
        #pragma unroll
        for (int j = 0; j < 8; ++j) s += psum[tid * 8 + j];
        pinv[tid] = 1.0f / s;
    }
    __syncthreads();

    if (wv < 2) {
        const int r = lane & 15, q = lane >> 4;
        const __bf16* bp  = vtb + ((size_t)(bh * HC + wv * 16 + r)) * SEQ + q * 8;
        const __bf16* apm = &pmat[r * PSTRIDE + q * 8];
        f32x4 acc = {0.f, 0.f, 0.f, 0.f};
        #pragma unroll
        for (int kt = 0; kt < SEQ; kt += 32) {
            bf16x8 af = *(const bf16x8*)(apm + kt);
            bf16x8 bf = *(const bf16x8*)(bp + kt);
            acc = __builtin_amdgcn_mfma_f32_16x16x32_bf16(af, bf, acc, 0, 0, 0);
        }
        const int b = bh >> 3, hh = bh & 7;
        const int c = wv * 16 + r;
        const int col = hh * HC + c;
        const float bpn = bproj[col];
        #pragma unroll
        for (int i = 0; i < 4; ++i) {
            const int tl = q * 4 + i;
            const int t  = qbase + tl;
            const float v = acc[i] * pinv[tl];
            const int idx = ((b * SEQ + t) * DM) + col;
            const float res = xin[idx] + v;
            x1[idx]  = res;
            out[idx] = res + bpn;      // base: x1 + bproj; K3 atomically adds h@Wproj
        }
    }
}

// ---------------------------------------------------------------------------
// K3: fused MLP, split-K x4, 512-thr blocks (round-2 structure, 1M atomics).
// NEW (this round): latency-hiding ILP via register prefetch —
//  (a) all 16 PROJ B-tiles (Wp) are loaded into VGPRs BEFORE the FC phase
//      (they depend on nothing FC computes; latency hides under FC),
//  (b) FC's 16 A-loads (x1 row slice) are hoisted+converted ahead of the
//      MFMA loop so every FC global load is in flight before first use.
// VGPR headroom: 512-thr block = 1 block/CU = 2 waves/SIMD => 256 regs OK.
// ---------------------------------------------------------------------------
#define HSTR 264

__global__ __launch_bounds__(512)
void mlp_k(const float* __restrict__ X1, const char* __restrict__ wsb,
           const float* __restrict__ bfc, float* __restrict__ out)
{
    __shared__ __align__(16) __bf16 hs[16 * HSTR];   // 8.25 KB
    const __bf16* Wf = (const __bf16*)(wsb + B_WFCT);
    const __bf16* Wp = (const __bf16*)(wsb + B_WPJT);

    const int tid  = threadIdx.x;
    const int lane = tid & 63;
    const int wv   = tid >> 6;                   // 0..7
    const int mt   = blockIdx.x & 63;
    const int ns   = blockIdx.x >> 6;            // k/n slab 0..3
    const int m0   = mt * 16;
    const int r    = lane & 15, q = lane >> 4;

    // ---- (a) prefetch all PROJ B tiles: independent of FC, hides under it ----
    bf16x8 wp[16];                               // 64 VGPRs
    #pragma unroll
    for (int kt8 = 0; kt8 < 8; ++kt8)
        #pragma unroll
        for (int nt = 0; nt < 2; ++nt)
            wp[kt8 * 2 + nt] = *(const bf16x8*)(Wp +
                (size_t)(wv * 32 + nt * 16 + r) * 1024 + ns * 256 + kt8 * 32 + q * 8);

    // ---- FC phase: h[16][ns*256 .. +256) ----
    {
        const float* ap = X1 + (size_t)(m0 + r) * DM + q * 8;

        // (b) hoist the full A row slice: all 16 loads issue before the loop
        bf16x8 afr[8];                           // 32 VGPRs
        #pragma unroll
        for (int kt8 = 0; kt8 < 8; ++kt8) {
            float4 a0 = *(const float4*)(ap + kt8 * 32);
            float4 a1 = *(const float4*)(ap + kt8 * 32 + 4);
            bf16x8 af;
            af[0] = (__bf16)a0.x; af[1] = (__bf16)a0.y; af[2] = (__bf16)a0.z; af[3] = (__bf16)a0.w;
            af[4] = (__bf16)a1.x; af[5] = (__bf16)a1.y; af[6] = (__bf16)a1.z; af[7] = (__bf16)a1.w;
            afr[kt8] = af;
        }

        f32x4 acc[2] = {};
        #pragma unroll
        for (int kt8 = 0; kt8 < 8; ++kt8) {
            #pragma unroll
            for (int nt = 0; nt < 2; ++nt) {
                const int n0 = ns * 256 + (wv * 2 + nt) * 16;       // global h col
                bf16x8 bf = *(const bf16x8*)(Wf + (size_t)(n0 + r) * DM + kt8 * 32 + q * 8);
                acc[nt] = __builtin_amdgcn_mfma_f32_16x16x32_bf16(afr[kt8], bf, acc[nt], 0, 0, 0);
            }
        }
        #pragma unroll
        for (int nt = 0; nt < 2; ++nt) {
            const int nl = (wv * 2 + nt) * 16 + r;                  // local 0..255
            const float bn = bfc[ns * 256 + nl];
            #pragma unroll
            for (int i = 0; i < 4; ++i)
                hs[(q * 4 + i) * HSTR + nl] = (__bf16)qgelu(acc[nt][i] + bn);
        }
    }
    __syncthreads();

    // ---- PROJ phase: out[m0..+16][wv*32..+32) += h_slab @ Wp k-slice ----
    {
        f32x4 acc[2] = {};
        const __bf16* al = &hs[r * HSTR + q * 8];                   // A row = m
        #pragma unroll
        for (int kt8 = 0; kt8 < 8; ++kt8) {
            bf16x8 af = *(const bf16x8*)(al + kt8 * 32);
            acc[0] = __builtin_amdgcn_mfma_f32_16x16x32_bf16(af, wp[kt8 * 2 + 0], acc[0], 0, 0, 0);
            acc[1] = __builtin_amdgcn_mfma_f32_16x16x32_bf16(af, wp[kt8 * 2 + 1], acc[1], 0, 0, 0);
        }
        #pragma unroll
        for (int nt = 0; nt < 2; ++nt) {
            const int n = wv * 32 + nt * 16 + r;
            #pragma unroll
            for (int i = 0; i < 4; ++i) {
                const int m = m0 + q * 4 + i;
                atomicAdd(&out[(size_t)m * DM + n], acc[nt][i]);
            }
        }
    }
}

// ---------------------------------------------------------------------------
extern "C" void kernel_launch(void* const* d_in, const int* in_sizes, int n_in,
                              void* d_out, int out_size, void* d_ws, size_t ws_size,
                              hipStream_t stream)
{
    (void)in_sizes; (void)n_in; (void)out_size; (void)ws_size;
    const float* x     = (const float*)d_in[0];
    const float* Wqkv  = (const float*)d_in[1];
    const float* bqkv  = (const float*)d_in[2];
    const float* Wfc   = (const float*)d_in[3];
    const float* bfc   = (const float*)d_in[4];
    const float* Wproj = (const float*)d_in[5];
    const float* bproj = (const float*)d_in[6];
    float* out = (float*)d_out;
    char*  wsb = (char*)d_ws;
    float* x1  = (float*)(wsb + B_X1);

    // K1: QKV GEMM (LDS-staged B panel) + side-car Wfc/Wproj transposes
    qkv_k<<<896, 256, 0, stream>>>(x, Wqkv, bqkv, Wfc, Wproj, wsb);

    // K2: attention + residual -> x1; pre-init out = x1 + bproj
    attn_k<<<512, 512, 0, stream>>>(wsb, x, x1, bproj, out);

    // K3: out += qgelu(x1@Wfc+b) @ Wproj  (split-K x4, reg-prefetched)
    mlp_k<<<256, 512, 0, stream>>>(x1, wsb, bfc, out);
}

// Round 5
// 106.171 us; speedup vs baseline: 1.7004x; 1.0007x over previous
//
#include <hip/hip_runtime.h>
#include <hip/hip_bf16.h>
#include <hip/hip_fp16.h>

// Problem constants
#define DM   256
#define NH   8
#define HC   32
#define SEQ  512
#define MTOT 1024

// ---------- workspace layout (byte offsets) ----------
#define B_X1   0            // fp32 x1 [1024][256]      1 MB
#define B_QH   (1u<<20)     // fp16 q  [16][512][32]    512 KB
#define B_KH   0x180000u    // fp16 k  [16][512][32]    512 KB
#define B_VT   0x200000u    // bf16 vT [16][32][512]    512 KB
#define B_WFCT 0x280000u    // bf16 WfcT  [1024][256]   512 KB
#define B_WPJT 0x300000u    // bf16 WprojT [256][1024]  512 KB

typedef __attribute__((ext_vector_type(8))) __bf16 bf16x8;
typedef __attribute__((ext_vector_type(4))) __bf16 bf16x4;
typedef __attribute__((ext_vector_type(4))) float  f32x4;

__device__ __forceinline__ float qgelu(float x) {
    return x / (1.0f + __expf(-1.702f * x));
}

// ---------------------------------------------------------------------------
// K1: QKV GEMM only (1024x768, K=256) — transpose side-car moved to K2.
// Exactly 768 blocks = 3 blocks/CU, no tail round. B-panel staged once
// through LDS; MFMA loop reads one ds_read_b128 per K-step.
// ---------------------------------------------------------------------------
#define BKP 264   // lbt row stride (k) in elements: 256 + 8 pad

__global__ __launch_bounds__(256)
void qkv_k(const float* __restrict__ x, const float* __restrict__ W,
           const float* __restrict__ bias, char* __restrict__ wsb)
{
    __shared__ __align__(16) __bf16 lbt[16 * BKP];   // B^T panel, 8.25 KB
    const int bid = blockIdx.x, tid = threadIdx.x;

    const int lane = tid & 63, wv = tid >> 6;
    const int n0 = (bid >> 4) * 16;                   // shared by all 4 waves
    const int m0 = ((bid * 4 + wv) & 63) * 16;
    const int r = lane & 15, q = lane >> 4;

    // ---- cooperative stage: W[0:256][n0:n0+16] -> lbt[n][k] bf16 ----
    {
        const int kk = tid >> 2;            // 0..63
        const int c4 = (tid & 3) * 4;       // 0,4,8,12
        #pragma unroll
        for (int p = 0; p < 4; ++p) {
            const int k = p * 64 + kk;
            float4 w = *(const float4*)&W[(size_t)k * 768 + n0 + c4];
            lbt[(c4 + 0) * BKP + k] = (__bf16)w.x;
            lbt[(c4 + 1) * BKP + k] = (__bf16)w.y;
            lbt[(c4 + 2) * BKP + k] = (__bf16)w.z;
            lbt[(c4 + 3) * BKP + k] = (__bf16)w.w;
        }
    }
    __syncthreads();

    const float*  ap = x + (size_t)(m0 + r) * DM + q * 8;
    const __bf16* bl = &lbt[r * BKP + q * 8];

    f32x4 acc = {0.f, 0.f, 0.f, 0.f};
    #pragma unroll
    for (int kt = 0; kt < DM; kt += 32) {
        float4 a0 = *(const float4*)(ap + kt);
        float4 a1 = *(const float4*)(ap + kt + 4);
        bf16x8 af;
        af[0] = (__bf16)a0.x; af[1] = (__bf16)a0.y; af[2] = (__bf16)a0.z; af[3] = (__bf16)a0.w;
        af[4] = (__bf16)a1.x; af[5] = (__bf16)a1.y; af[6] = (__bf16)a1.z; af[7] = (__bf16)a1.w;
        bf16x8 bf = *(const bf16x8*)(bl + kt);
        acc = __builtin_amdgcn_mfma_f32_16x16x32_bf16(af, bf, acc, 0, 0, 0);
    }

    __half*  qh  = (__half*)(wsb + B_QH);
    __half*  kh  = (__half*)(wsb + B_KH);
    __bf16*  vtb = (__bf16*)(wsb + B_VT);
    const int n = n0 + r;                 // C col = lane&15
    const float bn = bias[n];
    const int h = n / 96, jj = n % 96;
    #pragma unroll
    for (int i = 0; i < 4; ++i) {
        const int m = m0 + q * 4 + i;     // C row = q*4 + i
        const float v = acc[i] + bn;
        const int b = m >> 9, t = m & 511;
        const int bh = b * NH + h;
        if (jj < 32)      qh[((size_t)(bh * SEQ + t)) * HC + jj]        = (__half)v;
        else if (jj < 64) kh[((size_t)(bh * SEQ + t)) * HC + (jj - 32)] = (__half)v;
        else              vtb[((size_t)(bh * HC + (jj - 64))) * SEQ + t] = (__bf16)v;
    }
}

// ---------------------------------------------------------------------------
// K2: L1-distance attention + residual. NEW this round:
//  (a) PV uses ALL 8 waves: wave w -> (c-tile = w&1, K-quarter = w>>1);
//      4x shorter serial MFMA chain, 4x V-load concurrency; partials
//      reduced via 8KB LDS; 512-thread epilogue (1 output elem/thread).
//  (b) side-car blocks 512..639 do the Wfc/Wproj 64x64 transposes
//      (moved out of K1; memory-bound work hides inside VALU-bound K2).
// ---------------------------------------------------------------------------
#define QT 16
#define PSTRIDE 514
// LDS carve (attention): pmat 16448 | qtile 1024 | psum 512 | pinv 64 | partial 8192
#define O_QTILE  16448
#define O_PSUM   17472
#define O_PINV   17984
#define O_PART   18048
#define SMSZ     26240   // transpose path needs 16640 <= SMSZ

__global__ __launch_bounds__(512, 4)
void attn_k(const char* __restrict__ wsb, const float* __restrict__ xin,
            float* __restrict__ x1, const float* __restrict__ bproj,
            const float* __restrict__ Wfc, const float* __restrict__ Wproj,
            float* __restrict__ out, char* __restrict__ wsw)
{
    __shared__ __align__(16) unsigned char SM[SMSZ];
    const int tid = threadIdx.x;
    const int bid = blockIdx.x;

    if (bid >= 512) {
        // ---- side-car: 64x64 transpose tiles of Wfc/Wproj -> bf16 [n][k] ----
        const int tt = bid - 512;
        const float* src; __bf16* dst; int K, N, tile;
        if (tt < 64) { src = Wfc;   dst = (__bf16*)(wsw + B_WFCT); K = 256;  N = 1024; tile = tt; }
        else         { src = Wproj; dst = (__bf16*)(wsw + B_WPJT); K = 1024; N = 256;  tile = tt - 64; }
        float* lt = (float*)SM;                       // [64][65] f32
        const int nn = N >> 6;
        const int k0 = (tile / nn) * 64, n0 = (tile % nn) * 64;
        const int rr0 = tid >> 4, c4 = tid & 15;      // rr0 0..31
        #pragma unroll
        for (int i = 0; i < 2; ++i) {
            const int rr = rr0 + i * 32;
            float4 v = *(const float4*)&src[(size_t)(k0 + rr) * N + n0 + c4 * 4];
            lt[rr * 65 + c4 * 4 + 0] = v.x; lt[rr * 65 + c4 * 4 + 1] = v.y;
            lt[rr * 65 + c4 * 4 + 2] = v.z; lt[rr * 65 + c4 * 4 + 3] = v.w;
        }
        __syncthreads();
        #pragma unroll
        for (int i = 0; i < 2; ++i) {
            const int rr = rr0 + i * 32;
            bf16x4 b;
            b.x = (__bf16)lt[(c4 * 4 + 0) * 65 + rr];
            b.y = (__bf16)lt[(c4 * 4 + 1) * 65 + rr];
            b.z = (__bf16)lt[(c4 * 4 + 2) * 65 + rr];
            b.w = (__bf16)lt[(c4 * 4 + 3) * 65 + rr];
            *(bf16x4*)&dst[(size_t)(n0 + rr) * K + k0 + c4 * 4] = b;
        }
        return;
    }

    __bf16*  pmat  = (__bf16*)SM;
    __half2* qtile = (__half2*)(SM + O_QTILE);
    float*   psum  = (float*)(SM + O_PSUM);
    float*   pinv  = (float*)(SM + O_PINV);
    float*   part  = (float*)(SM + O_PART);

    const __half*  qhg = (const __half*)(wsb + B_QH);
    const __half*  khg = (const __half*)(wsb + B_KH);
    const __bf16*  vtb = (const __bf16*)(wsb + B_VT);

    const int lane = tid & 63;
    const int wv   = tid >> 6;
    const int sg   = tid;                       // s index
    const int bh   = bid >> 5;
    const int qbase = (bid & 31) * QT;
    const float scale = 0.17677669529663687f;   // 1/sqrt(32)

    const __half2* kp = (const __half2*)(khg + ((size_t)(bh * SEQ + sg)) * HC);
    __half2 kr[16];
    #pragma unroll
    for (int j = 0; j < 16; ++j) kr[j] = kp[j];

    if (tid < 256) {
        const int t = tid >> 4, j = tid & 15;
        qtile[t * 16 + j] =
            *(const __half2*)(qhg + ((size_t)(bh * SEQ + qbase + t)) * HC + j * 2);
    }
    __syncthreads();

    #pragma unroll 4
    for (int t = 0; t < QT; ++t) {
        __half2 acc2 = __floats2half2_rn(0.f, 0.f);
        #pragma unroll
        for (int j = 0; j < 16; ++j) {
            __half2 dif = __hsub2(kr[j], qtile[t * 16 + j]);   // LDS broadcast
            unsigned u = (*(unsigned*)&dif) & 0x7FFF7FFFu;     // packed |.|
            acc2 = __hadd2(acc2, *(__half2*)&u);
        }
        const float d = __low2float(acc2) + __high2float(acc2);
        float w = 1.0f / (0.001f + d * scale);
        if (sg == qbase + t) w = 0.0f;          // diagonal
        float p = __expf(w);                    // w bounded: no max pass
        float se = p;
        #pragma unroll
        for (int off = 32; off >= 1; off >>= 1) se += __shfl_xor(se, off, 64);
        pmat[t * PSTRIDE + sg] = (__bf16)p;
        if (lane == 0) psum[t * 8 + wv] = se;
    }
    __syncthreads();

    if (tid < QT) {
        float s = 0.f;
        #pragma unroll
        for (int j = 0; j < 8; ++j) s += psum[tid * 8 + j];
        pinv[tid] = 1.0f / s;
    }
    __syncthreads();

    // ---- PV: all 8 waves. wave wv -> c-tile nc = wv&1, K-quarter ks = wv>>1 ----
    {
        const int r = lane & 15, q = lane >> 4;
        const int nc = wv & 1, ks = wv >> 1;
        const __bf16* bp  = vtb + ((size_t)(bh * HC + nc * 16 + r)) * SEQ + ks * 128 + q * 8;
        const __bf16* apm = &pmat[r * PSTRIDE + ks * 128 + q * 8];
        f32x4 acc = {0.f, 0.f, 0.f, 0.f};
        #pragma unroll
        for (int kt = 0; kt < 128; kt += 32) {
            bf16x8 af = *(const bf16x8*)(apm + kt);
            bf16x8 bf = *(const bf16x8*)(bp + kt);
            acc = __builtin_amdgcn_mfma_f32_16x16x32_bf16(af, bf, acc, 0, 0, 0);
        }
        *(f32x4*)&part[wv * 256 + lane * 4] = acc;   // ds_write_b128, conflict-free
    }
    __syncthreads();

    // ---- reduce 4 K-partials + epilogue: one output element per thread ----
    {
        const int nc  = tid >> 8;            // c-tile 0/1
        const int idx = tid & 255;           // lane*4+i within tile
        float s = part[(0 * 2 + nc) * 256 + idx] + part[(1 * 2 + nc) * 256 + idx]
                + part[(2 * 2 + nc) * 256 + idx] + part[(3 * 2 + nc) * 256 + idx];
        const int colr = (idx >> 2) & 15;                 // C col = lane&15
        const int tl   = ((idx >> 6) << 2) + (idx & 3);   // C row = q*4+i
        const int t    = qbase + tl;
        const int b = bh >> 3, hh = bh & 7;
        const int col = hh * HC + nc * 16 + colr;
        const float v = s * pinv[tl];
        const int idxg = ((b * SEQ + t) * DM) + col;
        const float res = xin[idxg] + v;
        x1[idxg]  = res;
        out[idxg] = res + bproj[col];   // base: x1 + bproj; K3 atomically adds h@Wproj
    }
}

// ---------------------------------------------------------------------------
// K3: fused MLP, split-K x4, 512-thr blocks, 1M atomics (round-4 version,
// reg-prefetched Wp + hoisted FC A-loads).
// ---------------------------------------------------------------------------
#define HSTR 264

__global__ __launch_bounds__(512)
void mlp_k(const float* __restrict__ X1, const char* __restrict__ wsb,
           const float* __restrict__ bfc, float* __restrict__ out)
{
    __shared__ __align__(16) __bf16 hs[16 * HSTR];   // 8.25 KB
    const __bf16* Wf = (const __bf16*)(wsb + B_WFCT);
    const __bf16* Wp = (const __bf16*)(wsb + B_WPJT);

    const int tid  = threadIdx.x;
    const int lane = tid & 63;
    const int wv   = tid >> 6;                   // 0..7
    const int mt   = blockIdx.x & 63;
    const int ns   = blockIdx.x >> 6;            // k/n slab 0..3
    const int m0   = mt * 16;
    const int r    = lane & 15, q = lane >> 4;

    // ---- prefetch all PROJ B tiles: independent of FC, hides under it ----
    bf16x8 wp[16];                               // 64 VGPRs
    #pragma unroll
    for (int kt8 = 0; kt8 < 8; ++kt8)
        #pragma unroll
        for (int nt = 0; nt < 2; ++nt)
            wp[kt8 * 2 + nt] = *(const bf16x8*)(Wp +
                (size_t)(wv * 32 + nt * 16 + r) * 1024 + ns * 256 + kt8 * 32 + q * 8);

    // ---- FC phase: h[16][ns*256 .. +256) ----
    {
        const float* ap = X1 + (size_t)(m0 + r) * DM + q * 8;

        bf16x8 afr[8];                           // 32 VGPRs
        #pragma unroll
        for (int kt8 = 0; kt8 < 8; ++kt8) {
            float4 a0 = *(const float4*)(ap + kt8 * 32);
            float4 a1 = *(const float4*)(ap + kt8 * 32 + 4);
            bf16x8 af;
            af[0] = (__bf16)a0.x; af[1] = (__bf16)a0.y; af[2] = (__bf16)a0.z; af[3] = (__bf16)a0.w;
            af[4] = (__bf16)a1.x; af[5] = (__bf16)a1.y; af[6] = (__bf16)a1.z; af[7] = (__bf16)a1.w;
            afr[kt8] = af;
        }

        f32x4 acc[2] = {};
        #pragma unroll
        for (int kt8 = 0; kt8 < 8; ++kt8) {
            #pragma unroll
            for (int nt = 0; nt < 2; ++nt) {
                const int n0 = ns * 256 + (wv * 2 + nt) * 16;       // global h col
                bf16x8 bf = *(const bf16x8*)(Wf + (size_t)(n0 + r) * DM + kt8 * 32 + q * 8);
                acc[nt] = __builtin_amdgcn_mfma_f32_16x16x32_bf16(afr[kt8], bf, acc[nt], 0, 0, 0);
            }
        }
        #pragma unroll
        for (int nt = 0; nt < 2; ++nt) {
            const int nl = (wv * 2 + nt) * 16 + r;                  // local 0..255
            const float bn = bfc[ns * 256 + nl];
            #pragma unroll
            for (int i = 0; i < 4; ++i)
                hs[(q * 4 + i) * HSTR + nl] = (__bf16)qgelu(acc[nt][i] + bn);
        }
    }
    __syncthreads();

    // ---- PROJ phase: out[m0..+16][wv*32..+32) += h_slab @ Wp k-slice ----
    {
        f32x4 acc[2] = {};
        const __bf16* al = &hs[r * HSTR + q * 8];                   // A row = m
        #pragma unroll
        for (int kt8 = 0; kt8 < 8; ++kt8) {
            bf16x8 af = *(const bf16x8*)(al + kt8 * 32);
            acc[0] = __builtin_amdgcn_mfma_f32_16x16x32_bf16(af, wp[kt8 * 2 + 0], acc[0], 0, 0, 0);
            acc[1] = __builtin_amdgcn_mfma_f32_16x16x32_bf16(af, wp[kt8 * 2 + 1], acc[1], 0, 0, 0);
        }
        #pragma unroll
        for (int nt = 0; nt < 2; ++nt) {
            const int n = wv * 32 + nt * 16 + r;
            #pragma unroll
            for (int i = 0; i < 4; ++i) {
                const int m = m0 + q * 4 + i;
                atomicAdd(&out[(size_t)m * DM + n], acc[nt][i]);
            }
        }
    }
}

// ---------------------------------------------------------------------------
extern "C" void kernel_launch(void* const* d_in, const int* in_sizes, int n_in,
                              void* d_out, int out_size, void* d_ws, size_t ws_size,
                              hipStream_t stream)
{
    (void)in_sizes; (void)n_in; (void)out_size; (void)ws_size;
    const float* x     = (const float*)d_in[0];
    const float* Wqkv  = (const float*)d_in[1];
    const float* bqkv  = (const float*)d_in[2];
    const float* Wfc   = (const float*)d_in[3];
    const float* bfc   = (const float*)d_in[4];
    const float* Wproj = (const float*)d_in[5];
    const float* bproj = (const float*)d_in[6];
    float* out = (float*)d_out;
    char*  wsb = (char*)d_ws;
    float* x1  = (float*)(wsb + B_X1);

    // K1: QKV GEMM only (768 blocks = 3/CU exactly)
    qkv_k<<<768, 256, 0, stream>>>(x, Wqkv, bqkv, wsb);

    // K2: attention (8-wave PV) + residual -> x1; out = x1 + bproj;
    //     blocks 512..639: Wfc/Wproj transposes for K3
    attn_k<<<640, 512, 0, stream>>>(wsb, x, x1, bproj, Wfc, Wproj, out, wsb);

    // K3: out += qgelu(x1@Wfc+b) @ Wproj  (split-K x4, reg-prefetched)
    mlp_k<<<256, 512, 0, stream>>>(x1, wsb, bfc, out);
}